// Round 5
// baseline (600.937 us; speedup 1.0000x reference)
//
#include <hip/hip_runtime.h>

// B=64, C=2, N=1024, T=13, D=256
// out: [B,N,N] fp32 = 268 MB; ws: centered ranks as int8 [B,N,D] = 16 MB

typedef __attribute__((ext_vector_type(4))) int i32x4;

__device__ __forceinline__ void load_lds16(const void* g, void* l) {
  __builtin_amdgcn_global_load_lds(
      (const __attribute__((address_space(1))) void*)g,
      (__attribute__((address_space(3))) void*)l, 16, 0, 0);
}

// ---------------------------------------------------------------------------
// K1: conv (bcnt,dct->bnd) + time-LayerNorm + Spearman rank -> (rank-128) int8
// 4 rows per block (256 threads); thread d owns dim d of all 4 rows.
// 4-way ILP through the bitonic network hides DS-pipe (shfl) latency, which
// was the round-2 bottleneck (VALUBusy 64%, one row/block = no ILP).
// ---------------------------------------------------------------------------
__global__ __launch_bounds__(256) void conv_rank_kernel(
    const float* __restrict__ x, const float* __restrict__ w,
    const float* __restrict__ cb, const float* __restrict__ tg,
    const float* __restrict__ tb, signed char* __restrict__ ranks)
{
  int grp = blockIdx.x;              // 16384 = 64 batches * 256 row-groups
  int b = grp >> 8;
  int n0 = (grp & 255) << 2;         // 4 consecutive rows
  int d = threadIdx.x;
  int wave = d >> 6, lane = d & 63;

  __shared__ float xs[104];          // [c2][r4][t13] contiguous per c
  __shared__ float red[4][8];
  __shared__ unsigned int ks[4][256];

  if (d < 104) {
    int c = d / 52, rem = d - c * 52;   // rem = r*13 + t
    xs[d] = x[((size_t)(b * 2 + c) * 1024 + n0) * 13 + rem];
  }

  // conv weights for dim d -> registers, reused across 4 rows
  float wd[26];
  const float* wp = w + d * 26;
  #pragma unroll
  for (int i = 0; i < 26; ++i) wd[i] = wp[i];
  float cbd = cb[d], tgd = tg[d], tbd = tb[d];
  __syncthreads();

  float accv[4];
  #pragma unroll
  for (int r = 0; r < 4; ++r) {
    float a = cbd;
    #pragma unroll
    for (int c = 0; c < 2; ++c)
      #pragma unroll
      for (int t = 0; t < 13; ++t)
        a += wd[c * 13 + t] * xs[c * 52 + r * 13 + t];
    accv[r] = a;
  }

  // time layernorm over D=256, 4 independent reductions (ILP)
  float v1[4], v2[4];
  #pragma unroll
  for (int r = 0; r < 4; ++r) { v1[r] = accv[r]; v2[r] = accv[r] * accv[r]; }
  #pragma unroll
  for (int o = 32; o > 0; o >>= 1) {
    #pragma unroll
    for (int r = 0; r < 4; ++r) {
      v1[r] += __shfl_down(v1[r], o);
      v2[r] += __shfl_down(v2[r], o);
    }
  }
  if (lane == 0) {
    #pragma unroll
    for (int r = 0; r < 4; ++r) { red[r][wave * 2] = v1[r]; red[r][wave * 2 + 1] = v2[r]; }
  }
  __syncthreads();

  unsigned int key[4], okey[4];
  #pragma unroll
  for (int r = 0; r < 4; ++r) {
    float s1 = red[r][0] + red[r][2] + red[r][4] + red[r][6];
    float s2 = red[r][1] + red[r][3] + red[r][5] + red[r][7];
    float mu = s1 * (1.0f / 256.0f);
    float var = s2 * (1.0f / 256.0f) - mu * mu;
    float rs = rsqrtf(var + 1e-5f);
    float val = (accv[r] - mu) * rs * tgd + tbd;
    unsigned int u = __float_as_uint(val);
    key[r] = (u & 0x80000000u) ? ~u : (u | 0x80000000u);
    okey[r] = key[r];
  }

  // bitonic sort ascending across 256 threads, 4 rows in parallel
  #pragma unroll
  for (int k = 2; k <= 256; k <<= 1) {
    #pragma unroll
    for (int j = k >> 1; j > 0; j >>= 1) {
      unsigned int pk[4];
      if (j < 64) {
        #pragma unroll
        for (int r = 0; r < 4; ++r) pk[r] = __shfl_xor(key[r], j);
      } else {
        #pragma unroll
        for (int r = 0; r < 4; ++r) ks[r][d] = key[r];
        __syncthreads();
        #pragma unroll
        for (int r = 0; r < 4; ++r) pk[r] = ks[r][d ^ j];
        __syncthreads();
      }
      bool keep_min = ((d & j) == 0) == ((d & k) == 0);
      #pragma unroll
      for (int r = 0; r < 4; ++r) {
        unsigned int mn = key[r] < pk[r] ? key[r] : pk[r];
        unsigned int mx = key[r] < pk[r] ? pk[r] : key[r];
        key[r] = keep_min ? mn : mx;
      }
    }
  }

  // sorted keys -> LDS; rank = lower_bound(okey), 4 independent searches
  #pragma unroll
  for (int r = 0; r < 4; ++r) ks[r][d] = key[r];
  __syncthreads();
  int pos[4] = {0, 0, 0, 0};
  #pragma unroll
  for (int s = 128; s > 0; s >>= 1) {
    #pragma unroll
    for (int r = 0; r < 4; ++r)
      pos[r] += (ks[r][pos[r] + s - 1] < okey[r]) ? s : 0;
  }
  #pragma unroll
  for (int r = 0; r < 4; ++r)
    ranks[(size_t)(b * 1024 + n0 + r) * 256 + d] = (signed char)(pos[r] - 128);
}

// ---------------------------------------------------------------------------
// K2 (fused): per batch S = R R^T (int8 MFMA, exact i32), adj = |S-64|*inv_den,
// LayerNorm over node axis + ReLU + store.
// Operand roles SWAPPED vs round 2: A = 1024-node panel, B = 32-row panel, so
// the C/D "row" index (quad*4+v) walks 4 CONSECUTIVE OUTPUT COLUMNS ->
// float4 stores (16x16B/thread instead of 64x4B) and an in-thread LN row sum.
// ---------------------------------------------------------------------------
__global__ __launch_bounds__(512, 4) void corr_ln_kernel(
    const signed char* __restrict__ ranks, const float* __restrict__ sg,
    const float* __restrict__ sb, float* __restrict__ out)
{
  // XCD-chunked swizzle: each XCD gets 256 consecutive work items = 8 batches
  // (8 x 256KB rank panels, L2-resident).
  int bid = blockIdx.x;
  int blk = (bid & 7) * 256 + (bid >> 3);
  int b  = blk >> 5;
  int n0 = (blk & 31) << 5;           // 32 rows
  const signed char* R = ranks + (size_t)b * 1024 * 256;
  float* O = out + ((size_t)b * 1024 + n0) * 1024;

  __shared__ __align__(16) signed char As[8192];    // [kt4][kq4][32][16]
  __shared__ __align__(16) signed char Bs[65536];   // [kq4][1024][16]
  __shared__ float red[8][64];                      // [wave][32 sum | 32 sq]
  __shared__ float stats[2][32];                    // mu, rs per row

  int tid = threadIdx.x;
  int wave = tid >> 6, lane = tid & 63;
  int fr = lane & 15, quad = lane >> 4;
  int cw = wave << 7;                 // 128-col strip per wave

  // stage A (32 rows x K=256) once: one 16B/thread issue
  {
    int o = tid * 16;
    int kt_a = o >> 11, kq = (o >> 9) & 3, r32 = (o >> 4) & 31;
    load_lds16(R + (size_t)(n0 + r32) * 256 + kt_a * 64 + kq * 16, As + o);
  }

  i32x4 acc[2][8] = {};   // [mi: row chunk][ni: col chunk]

  for (int kt = 0; kt < 4; ++kt) {
    #pragma unroll
    for (int i = 0; i < 8; ++i) {
      int o = i * 8192 + tid * 16;
      int kq = o >> 14, row = (o & 16383) >> 4;
      load_lds16(R + (size_t)row * 256 + kt * 64 + kq * 16, Bs + o);
    }
    __syncthreads();   // drains vmcnt (covers As on kt=0)

    // B operand: the 32 output rows (B-side index = fr)
    i32x4 bfr[2];
    #pragma unroll
    for (int mi = 0; mi < 2; ++mi)
      bfr[mi] = *(const i32x4*)(As + kt * 2048 + quad * 512 + (mi * 16 + fr) * 16);
    // A operand: the 1024-col panel (A-side index = quad*4+v)
    #pragma unroll
    for (int ni = 0; ni < 8; ++ni) {
      i32x4 afc = *(const i32x4*)(Bs + quad * 16384 + (cw + ni * 16 + fr) * 16);
      acc[0][ni] = __builtin_amdgcn_mfma_i32_16x16x64_i8(afc, bfr[0], acc[0][ni], 0, 0, 0);
      acc[1][ni] = __builtin_amdgcn_mfma_i32_16x16x64_i8(afc, bfr[1], acc[1][ni], 0, 0, 0);
    }
    __syncthreads();
  }

  // value(mi,ni,v) = adj[row = mi*16 + fr][col = cw + ni*16 + quad*4 + v]
  float nrm = sqrtf(1398080.0f);
  float inv_den = 1.0f / (nrm * nrm + 1e-8f);

  // LN pass 1: in-thread row sums over this wave's strip, then quad reduce
  float sum[2], sq[2];
  #pragma unroll
  for (int mi = 0; mi < 2; ++mi) {
    float ss = 0.0f, qq = 0.0f;
    #pragma unroll
    for (int ni = 0; ni < 8; ++ni)
      #pragma unroll
      for (int v = 0; v < 4; ++v) {
        float a = fabsf((float)(acc[mi][ni][v] - 64)) * inv_den;
        ss += a; qq += a * a;
      }
    ss += __shfl_xor(ss, 16); ss += __shfl_xor(ss, 32);
    qq += __shfl_xor(qq, 16); qq += __shfl_xor(qq, 32);
    sum[mi] = ss; sq[mi] = qq;
  }
  if (quad == 0) {
    #pragma unroll
    for (int mi = 0; mi < 2; ++mi) {
      red[wave][mi * 16 + fr] = sum[mi];
      red[wave][32 + mi * 16 + fr] = sq[mi];
    }
  }
  __syncthreads();

  if (tid < 32) {
    float su = 0.0f, s2 = 0.0f;
    #pragma unroll
    for (int ww = 0; ww < 8; ++ww) { su += red[ww][tid]; s2 += red[ww][32 + tid]; }
    float mu = su * (1.0f / 1024.0f);
    float var = s2 * (1.0f / 1024.0f) - mu * mu;
    stats[0][tid] = mu;
    stats[1][tid] = rsqrtf(var + 1e-5f);
  }
  __syncthreads();

  // pass 2: normalize + ReLU + float4 stores
  #pragma unroll
  for (int mi = 0; mi < 2; ++mi) {
    int row = mi * 16 + fr;
    float mu = stats[0][row], rs = stats[1][row];
    float* orow = O + (size_t)row * 1024 + cw;
    #pragma unroll
    for (int ni = 0; ni < 8; ++ni) {
      float4 g4 = ((const float4*)sg)[(cw >> 2) + ni * 4 + quad];
      float4 b4 = ((const float4*)sb)[(cw >> 2) + ni * 4 + quad];
      float4 o4;
      float a0 = fabsf((float)(acc[mi][ni][0] - 64)) * inv_den;
      float a1 = fabsf((float)(acc[mi][ni][1] - 64)) * inv_den;
      float a2 = fabsf((float)(acc[mi][ni][2] - 64)) * inv_den;
      float a3 = fabsf((float)(acc[mi][ni][3] - 64)) * inv_den;
      o4.x = fmaxf(0.0f, (a0 - mu) * rs * g4.x + b4.x);
      o4.y = fmaxf(0.0f, (a1 - mu) * rs * g4.y + b4.y);
      o4.z = fmaxf(0.0f, (a2 - mu) * rs * g4.z + b4.z);
      o4.w = fmaxf(0.0f, (a3 - mu) * rs * g4.w + b4.w);
      ((float4*)(orow + ni * 16))[quad] = o4;
    }
  }
}

extern "C" void kernel_launch(void* const* d_in, const int* in_sizes, int n_in,
                              void* d_out, int out_size, void* d_ws, size_t ws_size,
                              hipStream_t stream) {
  const float* x  = (const float*)d_in[0];
  const float* w  = (const float*)d_in[1];
  const float* cb = (const float*)d_in[2];
  const float* tg = (const float*)d_in[3];
  const float* tb = (const float*)d_in[4];
  const float* sg = (const float*)d_in[5];
  const float* sb = (const float*)d_in[6];
  float* out = (float*)d_out;
  signed char* ranks = (signed char*)d_ws;  // 64*1024*256 = 16 MB

  conv_rank_kernel<<<16384, 256, 0, stream>>>(x, w, cb, tg, tb, ranks);
  corr_ln_kernel<<<2048, 512, 0, stream>>>(ranks, sg, sb, out);
}

// Round 6
// 529.850 us; speedup vs baseline: 1.1342x; 1.1342x over previous
//
#include <hip/hip_runtime.h>

// B=64, C=2, N=1024, T=13, D=256
// out: [B,N,N] fp32 = 268 MB; ws: centered ranks as int8 [B,N,D] = 16 MB

typedef __attribute__((ext_vector_type(4))) int i32x4;

__device__ __forceinline__ void load_lds16(const void* g, void* l) {
  __builtin_amdgcn_global_load_lds(
      (const __attribute__((address_space(1))) void*)g,
      (__attribute__((address_space(3))) void*)l, 16, 0, 0);
}

// ---------------------------------------------------------------------------
// K1: conv (bcnt,dct->bnd) + time-LayerNorm + Spearman rank -> (rank-128) int8
// WAVE-LOCAL: one row per wave, element e = i*64+lane (4 values/lane).
// Bitonic j<64 substeps = shfl_xor (no LDS/barrier); j=64,128 = in-register
// compare-exchange (free). LN = in-wave butterfly. Barriers/block: 9 -> 2.
// Round-5 post-mortem: block-wide barriers + LDS roundtrips were the ~100us
// non-VALU critical path (VALUBusy 50%, time flat at 207us).
// ---------------------------------------------------------------------------
__global__ __launch_bounds__(256) void conv_rank_kernel(
    const float* __restrict__ x, const float* __restrict__ w,
    const float* __restrict__ cb, const float* __restrict__ tg,
    const float* __restrict__ tb, signed char* __restrict__ ranks)
{
  int grp = blockIdx.x;              // 16384 = 64 batches * 256 row-groups
  int b = grp >> 8;
  int n0 = (grp & 255) << 2;         // 4 rows, one per wave
  int tid = threadIdx.x;
  int wave = tid >> 6, lane = tid & 63;
  int row = b * 1024 + n0 + wave;    // this wave's row

  __shared__ float xs[4][26];        // [r][c*13+t]
  __shared__ unsigned int ws[4][256];

  if (tid < 104) {
    int c = tid / 52, rem = tid - c * 52;   // rem = r*13 + t
    int r = rem / 13, t = rem - r * 13;
    xs[r][c * 13 + t] = x[((size_t)(b * 2 + c) * 1024 + n0 + r) * 13 + t];
  }
  __syncthreads();

  // conv: 4 dims d = i*64+lane; w row = 26 floats = 13 float2 (8B aligned)
  float accv[4];
  #pragma unroll
  for (int i = 0; i < 4; ++i) {
    int d = i * 64 + lane;
    const float2* wp = (const float2*)(w + d * 26);
    float a = cb[d];
    #pragma unroll
    for (int u = 0; u < 13; ++u) {
      float2 w2 = wp[u];
      a += w2.x * xs[wave][2 * u] + w2.y * xs[wave][2 * u + 1];
    }
    accv[i] = a;
  }

  // time layernorm over D=256: in-lane 4 + 6-level butterfly (all lanes get sums)
  float s1 = accv[0] + accv[1] + accv[2] + accv[3];
  float s2 = accv[0] * accv[0] + accv[1] * accv[1] +
             accv[2] * accv[2] + accv[3] * accv[3];
  #pragma unroll
  for (int o = 1; o < 64; o <<= 1) {
    s1 += __shfl_xor(s1, o);
    s2 += __shfl_xor(s2, o);
  }
  float mu = s1 * (1.0f / 256.0f);
  float var = s2 * (1.0f / 256.0f) - mu * mu;
  float rs = rsqrtf(var + 1e-5f);

  // monotone sortable u32 keys
  unsigned int key[4], okey[4];
  #pragma unroll
  for (int i = 0; i < 4; ++i) {
    int d = i * 64 + lane;
    float val = (accv[i] - mu) * rs * tg[d] + tb[d];
    unsigned int u = __float_as_uint(val);
    key[i] = (u & 0x80000000u) ? ~u : (u | 0x80000000u);
    okey[i] = key[i];
  }

  // bitonic sort ascending over e = i*64+lane (value-only, tie-safe)
  #pragma unroll
  for (int k = 2; k <= 256; k <<= 1) {
    #pragma unroll
    for (int j = k >> 1; j > 0; j >>= 1) {
      if (j < 64) {
        #pragma unroll
        for (int i = 0; i < 4; ++i) {
          unsigned int pk = __shfl_xor(key[i], j);
          int e = i * 64 + lane;
          bool km = ((e & j) == 0) == ((e & k) == 0);
          unsigned int mn = key[i] < pk ? key[i] : pk;
          unsigned int mx = key[i] < pk ? pk : key[i];
          key[i] = km ? mn : mx;
        }
      } else {
        int di = j >> 6;             // 1 or 2 (register exchange across i)
        #pragma unroll
        for (int i = 0; i < 4; ++i) {
          if ((i & di) == 0) {
            int ip = i + di;
            int e = i * 64 + lane;   // low element of the pair ((e&j)==0)
            bool up = ((e & k) == 0);
            unsigned int a = key[i], bb = key[ip];
            unsigned int mn = a < bb ? a : bb;
            unsigned int mx = a < bb ? bb : a;
            key[i]  = up ? mn : mx;
            key[ip] = up ? mx : mn;
          }
        }
      }
    }
  }

  // sorted keys -> wave-private LDS; rank = lower_bound(okey)
  #pragma unroll
  for (int i = 0; i < 4; ++i) ws[wave][i * 64 + lane] = key[i];
  __syncthreads();
  int pos[4] = {0, 0, 0, 0};
  #pragma unroll
  for (int s = 128; s > 0; s >>= 1) {
    #pragma unroll
    for (int i = 0; i < 4; ++i)
      pos[i] += (ws[wave][pos[i] + s - 1] < okey[i]) ? s : 0;
  }
  #pragma unroll
  for (int i = 0; i < 4; ++i)
    ranks[(size_t)row * 256 + i * 64 + lane] = (signed char)(pos[i] - 128);
}

// ---------------------------------------------------------------------------
// K2 (fused, round-2 measured-best version): per batch S = R R^T (int8 MFMA,
// exact i32), adj = |S-64|*inv_den, LayerNorm over node axis + ReLU + store.
// Block = 512 threads (8 waves), 32 rows x 1024 cols, K=256.
// LDS tiles k-quad-major [kq][row][16B] -> 2-way (free) bank aliasing.
// ---------------------------------------------------------------------------
__global__ __launch_bounds__(512, 4) void corr_ln_kernel(
    const signed char* __restrict__ ranks, const float* __restrict__ sg,
    const float* __restrict__ sb, float* __restrict__ out)
{
  // XCD-chunked swizzle: each XCD gets 256 consecutive work items = 8 batches
  // (8 x 256KB rank panels, L2-resident).
  int bid = blockIdx.x;
  int blk = (bid & 7) * 256 + (bid >> 3);
  int b  = blk >> 5;
  int n0 = (blk & 31) << 5;           // 32 rows
  const signed char* R = ranks + (size_t)b * 1024 * 256;
  float* O = out + ((size_t)b * 1024 + n0) * 1024;

  __shared__ __align__(16) signed char As[8192];    // [kt4][kq4][32][16]
  __shared__ __align__(16) signed char Bs[65536];   // [kq4][1024][16]
  __shared__ float red[8][64];                      // [wave][32 sum | 32 sq]
  __shared__ float stats[2][32];                    // mu, rs per row

  int tid = threadIdx.x;
  int wave = tid >> 6, lane = tid & 63;
  int fr = lane & 15, quad = lane >> 4;
  int cw = wave << 7;                 // 128-col strip per wave

  // stage A (32 rows x K=256) once: one 16B/thread issue
  {
    int o = tid * 16;
    int kt_a = o >> 11, kq = (o >> 9) & 3, r32 = (o >> 4) & 31;
    load_lds16(R + (size_t)(n0 + r32) * 256 + kt_a * 64 + kq * 16, As + o);
  }

  i32x4 acc[2][8] = {};

  for (int kt = 0; kt < 4; ++kt) {
    #pragma unroll
    for (int i = 0; i < 8; ++i) {
      int o = i * 8192 + tid * 16;
      int kq = o >> 14, row = (o & 16383) >> 4;
      load_lds16(R + (size_t)row * 256 + kt * 64 + kq * 16, Bs + o);
    }
    __syncthreads();   // drains vmcnt (covers As on kt=0)

    i32x4 af0 = *(const i32x4*)(As + kt * 2048 + quad * 512 + fr * 16);
    i32x4 af1 = *(const i32x4*)(As + kt * 2048 + quad * 512 + (16 + fr) * 16);
    #pragma unroll
    for (int ni = 0; ni < 8; ++ni) {
      i32x4 bf = *(const i32x4*)(Bs + quad * 16384 + (cw + ni * 16 + fr) * 16);
      acc[0][ni] = __builtin_amdgcn_mfma_i32_16x16x64_i8(af0, bf, acc[0][ni], 0, 0, 0);
      acc[1][ni] = __builtin_amdgcn_mfma_i32_16x16x64_i8(af1, bf, acc[1][ni], 0, 0, 0);
    }
    __syncthreads();
  }

  // adj = |S - 64| * inv_den  (exact int S)
  float nrm = sqrtf(1398080.0f);
  float inv_den = 1.0f / (nrm * nrm + 1e-8f);

  // LN pass 1: per-row partial sums over this wave's 128-col strip
  float s[2][4], q[2][4];
  #pragma unroll
  for (int mi = 0; mi < 2; ++mi) {
    #pragma unroll
    for (int v = 0; v < 4; ++v) {
      float ss = 0.0f, qq = 0.0f;
      #pragma unroll
      for (int ni = 0; ni < 8; ++ni) {
        float a = fabsf((float)(acc[mi][ni][v] - 64)) * inv_den;
        ss += a; qq += a * a;
      }
      #pragma unroll
      for (int o = 8; o > 0; o >>= 1) {   // reduce across the 16-lane group
        ss += __shfl_xor(ss, o);
        qq += __shfl_xor(qq, o);
      }
      s[mi][v] = ss; q[mi][v] = qq;
    }
  }
  if (fr == 0) {
    #pragma unroll
    for (int mi = 0; mi < 2; ++mi)
      #pragma unroll
      for (int v = 0; v < 4; ++v) {
        int r = mi * 16 + quad * 4 + v;
        red[wave][r] = s[mi][v];
        red[wave][32 + r] = q[mi][v];
      }
  }
  __syncthreads();

  if (tid < 32) {
    float su = 0.0f, sq = 0.0f;
    #pragma unroll
    for (int ww = 0; ww < 8; ++ww) { su += red[ww][tid]; sq += red[ww][32 + tid]; }
    float mu = su * (1.0f / 1024.0f);
    float var = sq * (1.0f / 1024.0f) - mu * mu;
    stats[0][tid] = mu;
    stats[1][tid] = rsqrtf(var + 1e-5f);
  }
  __syncthreads();

  // pass 2: normalize + ReLU + store
  float gv[8], bv[8];
  #pragma unroll
  for (int ni = 0; ni < 8; ++ni) {
    int col = cw + ni * 16 + fr;
    gv[ni] = sg[col];
    bv[ni] = sb[col];
  }
  #pragma unroll
  for (int mi = 0; mi < 2; ++mi) {
    #pragma unroll
    for (int v = 0; v < 4; ++v) {
      int r = mi * 16 + quad * 4 + v;
      float mu = stats[0][r], rs = stats[1][r];
      float* orow = O + (size_t)r * 1024;
      #pragma unroll
      for (int ni = 0; ni < 8; ++ni) {
        float a = fabsf((float)(acc[mi][ni][v] - 64)) * inv_den;
        orow[cw + ni * 16 + fr] = fmaxf(0.0f, (a - mu) * rs * gv[ni] + bv[ni]);
      }
    }
  }
}

extern "C" void kernel_launch(void* const* d_in, const int* in_sizes, int n_in,
                              void* d_out, int out_size, void* d_ws, size_t ws_size,
                              hipStream_t stream) {
  const float* x  = (const float*)d_in[0];
  const float* w  = (const float*)d_in[1];
  const float* cb = (const float*)d_in[2];
  const float* tg = (const float*)d_in[3];
  const float* tb = (const float*)d_in[4];
  const float* sg = (const float*)d_in[5];
  const float* sb = (const float*)d_in[6];
  float* out = (float*)d_out;
  signed char* ranks = (signed char*)d_ws;  // 64*1024*256 = 16 MB

  conv_rank_kernel<<<16384, 256, 0, stream>>>(x, w, cb, tg, tb, ranks);
  corr_ln_kernel<<<2048, 512, 0, stream>>>(ranks, sg, sb, out);
}

// Round 7
// 501.706 us; speedup vs baseline: 1.1978x; 1.0561x over previous
//
#include <hip/hip_runtime.h>

// B=64, C=2, N=1024, T=13, D=256
// out: [B,N,N] fp32 = 268 MB; ws: centered ranks as int8 [B,N,D] = 16 MB

typedef __attribute__((ext_vector_type(4))) int i32x4;

__device__ __forceinline__ void load_lds16(const void* g, void* l) {
  __builtin_amdgcn_global_load_lds(
      (const __attribute__((address_space(1))) void*)g,
      (__attribute__((address_space(3))) void*)l, 16, 0, 0);
}

// ---------------------------------------------------------------------------
// K1: conv (bcnt,dct->bnd) + time-LayerNorm + Spearman rank -> (rank-128) int8
// Wave-local, one row per wave. PAYLOAD bitonic sort of u64 (key<<32|idx):
// sorted position = rank (exact stable argsort(argsort) semantics). Removes
// the 8-step divergent binary search (32 dependent ds_reads, 1.6e7 conflict
// cycles) and the final barrier.
// ---------------------------------------------------------------------------
__global__ __launch_bounds__(256) void conv_rank_kernel(
    const float* __restrict__ x, const float* __restrict__ w,
    const float* __restrict__ cb, const float* __restrict__ tg,
    const float* __restrict__ tb, signed char* __restrict__ ranks)
{
  int grp = blockIdx.x;              // 16384 = 64 batches * 256 row-groups
  int b = grp >> 8;
  int n0 = (grp & 255) << 2;         // 4 rows, one per wave
  int tid = threadIdx.x;
  int wave = tid >> 6, lane = tid & 63;
  int row = b * 1024 + n0 + wave;

  __shared__ float xs[4][26];

  if (tid < 104) {
    int c = tid / 52, rem = tid - c * 52;   // rem = r*13 + t
    int r = rem / 13, t = rem - r * 13;
    xs[r][c * 13 + t] = x[((size_t)(b * 2 + c) * 1024 + n0 + r) * 13 + t];
  }
  __syncthreads();

  // conv: 4 dims d = i*64+lane; w row = 26 floats = 13 float2
  float accv[4];
  #pragma unroll
  for (int i = 0; i < 4; ++i) {
    int d = i * 64 + lane;
    const float2* wp = (const float2*)(w + d * 26);
    float a = cb[d];
    #pragma unroll
    for (int u = 0; u < 13; ++u) {
      float2 w2 = wp[u];
      a += w2.x * xs[wave][2 * u] + w2.y * xs[wave][2 * u + 1];
    }
    accv[i] = a;
  }

  // time layernorm over D=256: in-lane 4 + 6-level butterfly
  float s1 = accv[0] + accv[1] + accv[2] + accv[3];
  float s2 = accv[0] * accv[0] + accv[1] * accv[1] +
             accv[2] * accv[2] + accv[3] * accv[3];
  #pragma unroll
  for (int o = 1; o < 64; o <<= 1) {
    s1 += __shfl_xor(s1, o);
    s2 += __shfl_xor(s2, o);
  }
  float mu = s1 * (1.0f / 256.0f);
  float var = s2 * (1.0f / 256.0f) - mu * mu;
  float rs = rsqrtf(var + 1e-5f);

  // u64 sort records: monotone key (hi 32) | element index (lo 8)
  unsigned long long kv[4];
  #pragma unroll
  for (int i = 0; i < 4; ++i) {
    int d = i * 64 + lane;
    float val = (accv[i] - mu) * rs * tg[d] + tb[d];
    unsigned int u = __float_as_uint(val);
    unsigned int key = (u & 0x80000000u) ? ~u : (u | 0x80000000u);
    kv[i] = ((unsigned long long)key << 32) | (unsigned int)d;
  }

  // bitonic sort ascending over e = i*64+lane (u64 records, no ties possible)
  #pragma unroll
  for (int k = 2; k <= 256; k <<= 1) {
    #pragma unroll
    for (int j = k >> 1; j > 0; j >>= 1) {
      if (j < 64) {
        #pragma unroll
        for (int i = 0; i < 4; ++i) {
          unsigned long long p = __shfl_xor(kv[i], j);
          int e = i * 64 + lane;
          bool km = ((e & j) == 0) == ((e & k) == 0);
          unsigned long long mn = kv[i] < p ? kv[i] : p;
          unsigned long long mx = kv[i] < p ? p : kv[i];
          kv[i] = km ? mn : mx;
        }
      } else {
        int di = j >> 6;             // 1 or 2 (register exchange across i)
        #pragma unroll
        for (int i = 0; i < 4; ++i) {
          if ((i & di) == 0) {
            int ip = i + di;
            int e = i * 64 + lane;   // low element of the pair
            bool up = ((e & k) == 0);
            unsigned long long a = kv[i], bb = kv[ip];
            unsigned long long mn = a < bb ? a : bb;
            unsigned long long mx = a < bb ? bb : a;
            kv[i]  = up ? mn : mx;
            kv[ip] = up ? mx : mn;
          }
        }
      }
    }
  }

  // sorted position e is the rank of element (kv[i] & 255); scatter int8
  signed char* rr = ranks + (size_t)row * 256;
  #pragma unroll
  for (int i = 0; i < 4; ++i) {
    int e = i * 64 + lane;
    rr[kv[i] & 255] = (signed char)(e - 128);
  }
}

// ---------------------------------------------------------------------------
// K2 (fused): per batch S = R R^T (int8 MFMA, exact i32), adj = |S-64|*inv_den,
// LayerNorm over node axis + ReLU + store. 8 waves, 32 rows x 1024 cols.
// NEW staging layout: row-major LDS with XOR chunk swizzle. Global reads are
// CONTIGUOUS per row (Bs: 16 rows x 64B per wave-instr; As: 4 rows x 256B) ->
// 4x fewer cache-line touches than the old 256B-stride 16B/lane pattern.
// Swizzled ds_read_b128 fragment reads are bank-uniform (8 lanes/4-bank grp).
// ---------------------------------------------------------------------------
__global__ __launch_bounds__(512, 4) void corr_ln_kernel(
    const signed char* __restrict__ ranks, const float* __restrict__ sg,
    const float* __restrict__ sb, float* __restrict__ out)
{
  // XCD-chunked swizzle: each XCD gets 256 consecutive work items = 8 batches
  int bid = blockIdx.x;
  int blk = (bid & 7) * 256 + (bid >> 3);
  int b  = blk >> 5;
  int n0 = (blk & 31) << 5;           // 32 rows
  const signed char* R = ranks + (size_t)b * 1024 * 256;
  float* O = out + ((size_t)b * 1024 + n0) * 1024;

  __shared__ __align__(16) signed char As[32 * 256];   // [r][c'], c' = c ^ (r&7)
  __shared__ __align__(16) signed char Bs[1024 * 64];  // [row][q'], q' = q ^ (row&3)
  __shared__ float red[8][64];                         // [wave][32 sum | 32 sq]
  __shared__ float stats[2][32];                       // mu, rs per row

  int tid = threadIdx.x;
  int wave = tid >> 6, lane = tid & 63;
  int fr = lane & 15, quad = lane >> 4;
  int cw = wave << 7;                 // 128-col strip per wave

  // stage A once (32 rows x 256B, full K): row = tid>>4, dest chunk c' = tid&15,
  // global chunk c = c' ^ (row&7). Per wave: 4 rows x 256B contiguous.
  {
    int r = tid >> 4, cp = tid & 15;
    int c = cp ^ (r & 7);
    load_lds16(R + (size_t)(n0 + r) * 256 + c * 16, As + tid * 16);
  }

  i32x4 acc[2][8] = {};

  for (int kt = 0; kt < 4; ++kt) {
    // stage B chunk: row = i*128 + tid>>2, dest q' = tid&3, global q = q'^(row&3)
    // Per wave-instr: 16 rows x 64B contiguous segments (permuted 16B chunks).
    #pragma unroll
    for (int i = 0; i < 8; ++i) {
      int r = i * 128 + (tid >> 2);
      int q = (tid & 3) ^ (r & 3);
      load_lds16(R + (size_t)r * 256 + kt * 64 + q * 16,
                 Bs + i * 8192 + tid * 16);
    }
    __syncthreads();   // drains vmcnt (covers As on kt=0)

    int csw = ((kt * 4 + quad) ^ (fr & 7)) << 4;   // swizzled A chunk offset
    i32x4 af0 = *(const i32x4*)(As + fr * 256 + csw);
    i32x4 af1 = *(const i32x4*)(As + (16 + fr) * 256 + csw);
    #pragma unroll
    for (int ni = 0; ni < 8; ++ni) {
      int rowb = cw + ni * 16 + fr;
      i32x4 bf = *(const i32x4*)(Bs + rowb * 64 + ((quad ^ (rowb & 3)) << 4));
      acc[0][ni] = __builtin_amdgcn_mfma_i32_16x16x64_i8(af0, bf, acc[0][ni], 0, 0, 0);
      acc[1][ni] = __builtin_amdgcn_mfma_i32_16x16x64_i8(af1, bf, acc[1][ni], 0, 0, 0);
    }
    __syncthreads();
  }

  // adj = |S - 64| * inv_den  (exact int S)
  float nrm = sqrtf(1398080.0f);
  float inv_den = 1.0f / (nrm * nrm + 1e-8f);

  // LN pass 1: per-row partial sums over this wave's 128-col strip
  float s[2][4], q[2][4];
  #pragma unroll
  for (int mi = 0; mi < 2; ++mi) {
    #pragma unroll
    for (int v = 0; v < 4; ++v) {
      float ss = 0.0f, qq = 0.0f;
      #pragma unroll
      for (int ni = 0; ni < 8; ++ni) {
        float a = fabsf((float)(acc[mi][ni][v] - 64)) * inv_den;
        ss += a; qq += a * a;
      }
      #pragma unroll
      for (int o = 8; o > 0; o >>= 1) {   // reduce across the 16-lane group
        ss += __shfl_xor(ss, o);
        qq += __shfl_xor(qq, o);
      }
      s[mi][v] = ss; q[mi][v] = qq;
    }
  }
  if (fr == 0) {
    #pragma unroll
    for (int mi = 0; mi < 2; ++mi)
      #pragma unroll
      for (int v = 0; v < 4; ++v) {
        int r = mi * 16 + quad * 4 + v;
        red[wave][r] = s[mi][v];
        red[wave][32 + r] = q[mi][v];
      }
  }
  __syncthreads();

  if (tid < 32) {
    float su = 0.0f, sq = 0.0f;
    #pragma unroll
    for (int ww = 0; ww < 8; ++ww) { su += red[ww][tid]; sq += red[ww][32 + tid]; }
    float mu = su * (1.0f / 1024.0f);
    float var = sq * (1.0f / 1024.0f) - mu * mu;
    stats[0][tid] = mu;
    stats[1][tid] = rsqrtf(var + 1e-5f);
  }
  __syncthreads();

  // pass 2: normalize + ReLU + store (round-2 measured-best pattern)
  float gv[8], bv[8];
  #pragma unroll
  for (int ni = 0; ni < 8; ++ni) {
    int col = cw + ni * 16 + fr;
    gv[ni] = sg[col];
    bv[ni] = sb[col];
  }
  #pragma unroll
  for (int mi = 0; mi < 2; ++mi) {
    #pragma unroll
    for (int v = 0; v < 4; ++v) {
      int r = mi * 16 + quad * 4 + v;
      float mu = stats[0][r], rs = stats[1][r];
      float* orow = O + (size_t)r * 1024;
      #pragma unroll
      for (int ni = 0; ni < 8; ++ni) {
        float a = fabsf((float)(acc[mi][ni][v] - 64)) * inv_den;
        orow[cw + ni * 16 + fr] = fmaxf(0.0f, (a - mu) * rs * gv[ni] + bv[ni]);
      }
    }
  }
}

extern "C" void kernel_launch(void* const* d_in, const int* in_sizes, int n_in,
                              void* d_out, int out_size, void* d_ws, size_t ws_size,
                              hipStream_t stream) {
  const float* x  = (const float*)d_in[0];
  const float* w  = (const float*)d_in[1];
  const float* cb = (const float*)d_in[2];
  const float* tg = (const float*)d_in[3];
  const float* tb = (const float*)d_in[4];
  const float* sg = (const float*)d_in[5];
  const float* sb = (const float*)d_in[6];
  float* out = (float*)d_out;
  signed char* ranks = (signed char*)d_ws;  // 64*1024*256 = 16 MB

  conv_rank_kernel<<<16384, 256, 0, stream>>>(x, w, cb, tg, tb, ranks);
  corr_ln_kernel<<<2048, 512, 0, stream>>>(ranks, sg, sb, out);
}

// Round 8
// 470.495 us; speedup vs baseline: 1.2772x; 1.0663x over previous
//
#include <hip/hip_runtime.h>

// B=64, C=2, N=1024, T=13, D=256
// out: [B,N,N] fp32 = 268 MB; ws: centered ranks as int8 [B,N,D] = 16 MB

typedef __attribute__((ext_vector_type(4))) int i32x4;

__device__ __forceinline__ void load_lds16(const void* g, void* l) {
  __builtin_amdgcn_global_load_lds(
      (const __attribute__((address_space(1))) void*)g,
      (__attribute__((address_space(3))) void*)l, 16, 0, 0);
}

// ---------------------------------------------------------------------------
// K1: conv (bcnt,dct->bnd) + time-LayerNorm + Spearman rank -> (rank-128) int8
// Round-6 measured-best (177us): wave-local 32-bit value bitonic sort
// (shfl_xor + in-register exchanges) + 8-step LDS binary search.
// (Round-7's u64 payload sort regressed to 254us: 2x DS + 1.5x VALU.)
// ---------------------------------------------------------------------------
__global__ __launch_bounds__(256) void conv_rank_kernel(
    const float* __restrict__ x, const float* __restrict__ w,
    const float* __restrict__ cb, const float* __restrict__ tg,
    const float* __restrict__ tb, signed char* __restrict__ ranks)
{
  int grp = blockIdx.x;              // 16384 = 64 batches * 256 row-groups
  int b = grp >> 8;
  int n0 = (grp & 255) << 2;         // 4 rows, one per wave
  int tid = threadIdx.x;
  int wave = tid >> 6, lane = tid & 63;
  int row = b * 1024 + n0 + wave;

  __shared__ float xs[4][26];
  __shared__ unsigned int ws[4][256];

  if (tid < 104) {
    int c = tid / 52, rem = tid - c * 52;   // rem = r*13 + t
    int r = rem / 13, t = rem - r * 13;
    xs[r][c * 13 + t] = x[((size_t)(b * 2 + c) * 1024 + n0 + r) * 13 + t];
  }
  __syncthreads();

  // conv: 4 dims d = i*64+lane; w row = 26 floats = 13 float2
  float accv[4];
  #pragma unroll
  for (int i = 0; i < 4; ++i) {
    int d = i * 64 + lane;
    const float2* wp = (const float2*)(w + d * 26);
    float a = cb[d];
    #pragma unroll
    for (int u = 0; u < 13; ++u) {
      float2 w2 = wp[u];
      a += w2.x * xs[wave][2 * u] + w2.y * xs[wave][2 * u + 1];
    }
    accv[i] = a;
  }

  // time layernorm over D=256: in-lane 4 + 6-level butterfly
  float s1 = accv[0] + accv[1] + accv[2] + accv[3];
  float s2 = accv[0] * accv[0] + accv[1] * accv[1] +
             accv[2] * accv[2] + accv[3] * accv[3];
  #pragma unroll
  for (int o = 1; o < 64; o <<= 1) {
    s1 += __shfl_xor(s1, o);
    s2 += __shfl_xor(s2, o);
  }
  float mu = s1 * (1.0f / 256.0f);
  float var = s2 * (1.0f / 256.0f) - mu * mu;
  float rs = rsqrtf(var + 1e-5f);

  // monotone sortable u32 keys
  unsigned int key[4], okey[4];
  #pragma unroll
  for (int i = 0; i < 4; ++i) {
    int d = i * 64 + lane;
    float val = (accv[i] - mu) * rs * tg[d] + tb[d];
    unsigned int u = __float_as_uint(val);
    key[i] = (u & 0x80000000u) ? ~u : (u | 0x80000000u);
    okey[i] = key[i];
  }

  // bitonic sort ascending over e = i*64+lane (value-only, tie-safe)
  #pragma unroll
  for (int k = 2; k <= 256; k <<= 1) {
    #pragma unroll
    for (int j = k >> 1; j > 0; j >>= 1) {
      if (j < 64) {
        #pragma unroll
        for (int i = 0; i < 4; ++i) {
          unsigned int pk = __shfl_xor(key[i], j);
          int e = i * 64 + lane;
          bool km = ((e & j) == 0) == ((e & k) == 0);
          unsigned int mn = key[i] < pk ? key[i] : pk;
          unsigned int mx = key[i] < pk ? pk : key[i];
          key[i] = km ? mn : mx;
        }
      } else {
        int di = j >> 6;             // 1 or 2 (register exchange across i)
        #pragma unroll
        for (int i = 0; i < 4; ++i) {
          if ((i & di) == 0) {
            int ip = i + di;
            int e = i * 64 + lane;   // low element of the pair
            bool up = ((e & k) == 0);
            unsigned int a = key[i], bb = key[ip];
            unsigned int mn = a < bb ? a : bb;
            unsigned int mx = a < bb ? bb : a;
            key[i]  = up ? mn : mx;
            key[ip] = up ? mx : mn;
          }
        }
      }
    }
  }

  // sorted keys -> wave-private LDS; rank = lower_bound(okey)
  #pragma unroll
  for (int i = 0; i < 4; ++i) ws[wave][i * 64 + lane] = key[i];
  __syncthreads();
  int pos[4] = {0, 0, 0, 0};
  #pragma unroll
  for (int s = 128; s > 0; s >>= 1) {
    #pragma unroll
    for (int i = 0; i < 4; ++i)
      pos[i] += (ws[wave][pos[i] + s - 1] < okey[i]) ? s : 0;
  }
  #pragma unroll
  for (int i = 0; i < 4; ++i)
    ranks[(size_t)row * 256 + i * 64 + lane] = (signed char)(pos[i] - 128);
}

// ---------------------------------------------------------------------------
// K2 (fused): per batch S = R R^T (int8 MFMA, exact i32), adj = |S-64|*inv_den,
// LayerNorm over node axis + ReLU + store. 8 waves, 32 rows x 1024 cols.
// WAVE-PRIVATE double-buffered B staging: each wave stages only its own
// 128-row strip (8KB/kt) into its own LDS region and syncs with a wave-level
// counted s_waitcnt vmcnt(N). ZERO block barriers in the k-loop (round-7 had
// 8 barrier drains/block = no stage/compute overlap). Swizzle + fragment math
// identical to round-7 (verified, conflicts ~0).
// ---------------------------------------------------------------------------
__global__ __launch_bounds__(512, 2) void corr_ln_kernel(
    const signed char* __restrict__ ranks, const float* __restrict__ sg,
    const float* __restrict__ sb, float* __restrict__ out)
{
  // XCD-chunked swizzle: each XCD gets 256 consecutive work items = 8 batches
  int bid = blockIdx.x;
  int blk = (bid & 7) * 256 + (bid >> 3);
  int b  = blk >> 5;
  int n0 = (blk & 31) << 5;           // 32 rows
  const signed char* R = ranks + (size_t)b * 1024 * 256;
  float* O = out + ((size_t)b * 1024 + n0) * 1024;

  __shared__ __align__(16) signed char As[32 * 256];      // [r][c'], c'=c^(r&7)
  __shared__ __align__(16) signed char Bs[8][2][8192];    // [wave][buf][128r][64B]
  __shared__ float red[8][64];                            // [wave][32 sum|32 sq]
  __shared__ float stats[2][32];

  int tid = threadIdx.x;
  int wave = tid >> 6, lane = tid & 63;
  int fr = lane & 15, quad = lane >> 4;
  int cw = wave << 7;                 // 128-col strip per wave

  // stage A once (32 rows x 256B full K, chunk-swizzled c' = c ^ (r&7))
  {
    int r = tid >> 4, cp = tid & 15;
    int c = cp ^ (r & 7);
    load_lds16(R + (size_t)(n0 + r) * 256 + c * 16, As + tid * 16);
  }

  // wave-private B staging: kt-tile kt -> buf p, 8 instrs, rows cw..cw+127
  signed char* myB = &Bs[wave][0][0];
  #define STAGE_B(kt, p)                                                      \
    {                                                                         \
      _Pragma("unroll")                                                       \
      for (int i = 0; i < 8; ++i) {                                           \
        int r = cw + i * 16 + (lane >> 2);                                    \
        int q = (lane & 3) ^ (r & 3);                                         \
        load_lds16(R + (size_t)r * 256 + (kt) * 64 + q * 16,                  \
                   myB + (p) * 8192 + i * 1024 + lane * 16);                  \
      }                                                                       \
    }

  STAGE_B(0, 0);
  __syncthreads();   // As + kt0 staged (drains vmcnt before barrier)

  i32x4 acc[2][8] = {};

  #pragma unroll
  for (int kt = 0; kt < 4; ++kt) {
    if (kt < 3) {
      STAGE_B(kt + 1, (kt + 1) & 1);
      asm volatile("s_waitcnt vmcnt(8)" ::: "memory");  // kt's 8 done, 8 in flight
    } else {
      asm volatile("s_waitcnt vmcnt(0)" ::: "memory");
    }
    __builtin_amdgcn_sched_barrier(0);

    const signed char* buf = myB + (kt & 1) * 8192;
    int csw = ((kt * 4 + quad) ^ (fr & 7)) << 4;   // swizzled A chunk offset
    i32x4 af0 = *(const i32x4*)(As + fr * 256 + csw);
    i32x4 af1 = *(const i32x4*)(As + (16 + fr) * 256 + csw);
    int bsw = (quad ^ (fr & 3)) << 4;              // swizzled B chunk offset
    #pragma unroll
    for (int ni = 0; ni < 8; ++ni) {
      i32x4 bf = *(const i32x4*)(buf + (ni * 16 + fr) * 64 + bsw);
      acc[0][ni] = __builtin_amdgcn_mfma_i32_16x16x64_i8(af0, bf, acc[0][ni], 0, 0, 0);
      acc[1][ni] = __builtin_amdgcn_mfma_i32_16x16x64_i8(af1, bf, acc[1][ni], 0, 0, 0);
    }
  }
  #undef STAGE_B

  // adj = |S - 64| * inv_den  (exact int S)
  float nrm = sqrtf(1398080.0f);
  float inv_den = 1.0f / (nrm * nrm + 1e-8f);

  // LN pass 1: per-row partial sums over this wave's 128-col strip
  float s[2][4], q[2][4];
  #pragma unroll
  for (int mi = 0; mi < 2; ++mi) {
    #pragma unroll
    for (int v = 0; v < 4; ++v) {
      float ss = 0.0f, qq = 0.0f;
      #pragma unroll
      for (int ni = 0; ni < 8; ++ni) {
        float a = fabsf((float)(acc[mi][ni][v] - 64)) * inv_den;
        ss += a; qq += a * a;
      }
      #pragma unroll
      for (int o = 8; o > 0; o >>= 1) {   // reduce across the 16-lane group
        ss += __shfl_xor(ss, o);
        qq += __shfl_xor(qq, o);
      }
      s[mi][v] = ss; q[mi][v] = qq;
    }
  }
  if (fr == 0) {
    #pragma unroll
    for (int mi = 0; mi < 2; ++mi)
      #pragma unroll
      for (int v = 0; v < 4; ++v) {
        int r = mi * 16 + quad * 4 + v;
        red[wave][r] = s[mi][v];
        red[wave][32 + r] = q[mi][v];
      }
  }
  __syncthreads();

  if (tid < 32) {
    float su = 0.0f, sq = 0.0f;
    #pragma unroll
    for (int ww = 0; ww < 8; ++ww) { su += red[ww][tid]; sq += red[ww][32 + tid]; }
    float mu = su * (1.0f / 1024.0f);
    float var = sq * (1.0f / 1024.0f) - mu * mu;
    stats[0][tid] = mu;
    stats[1][tid] = rsqrtf(var + 1e-5f);
  }
  __syncthreads();

  // pass 2: normalize + ReLU + store
  float gv[8], bv[8];
  #pragma unroll
  for (int ni = 0; ni < 8; ++ni) {
    int col = cw + ni * 16 + fr;
    gv[ni] = sg[col];
    bv[ni] = sb[col];
  }
  #pragma unroll
  for (int mi = 0; mi < 2; ++mi) {
    #pragma unroll
    for (int v = 0; v < 4; ++v) {
      int r = mi * 16 + quad * 4 + v;
      float mu = stats[0][r], rs = stats[1][r];
      float* orow = O + (size_t)r * 1024;
      #pragma unroll
      for (int ni = 0; ni < 8; ++ni) {
        float a = fabsf((float)(acc[mi][ni][v] - 64)) * inv_den;
        orow[cw + ni * 16 + fr] = fmaxf(0.0f, (a - mu) * rs * gv[ni] + bv[ni]);
      }
    }
  }
}

extern "C" void kernel_launch(void* const* d_in, const int* in_sizes, int n_in,
                              void* d_out, int out_size, void* d_ws, size_t ws_size,
                              hipStream_t stream) {
  const float* x  = (const float*)d_in[0];
  const float* w  = (const float*)d_in[1];
  const float* cb = (const float*)d_in[2];
  const float* tg = (const float*)d_in[3];
  const float* tb = (const float*)d_in[4];
  const float* sg = (const float*)d_in[5];
  const float* sb = (const float*)d_in[6];
  float* out = (float*)d_out;
  signed char* ranks = (signed char*)d_ws;  // 64*1024*256 = 16 MB

  conv_rank_kernel<<<16384, 256, 0, stream>>>(x, w, cb, tg, tb, ranks);
  corr_ln_kernel<<<2048, 512, 0, stream>>>(ranks, sg, sb, out);
}